// Round 1
// baseline (27.699 us; speedup 1.0000x reference)
//
#include <hip/hip_runtime.h>

#define DMODEL 512
#define BLOCKLEN 400
#define STRIDE 50
#define PER_BLK 8   // BLOCKLEN / STRIDE

// ---------------------------------------------------------------------------
// Stage 1: for each of the 11 "mean rows" (10 block-means + 1 global mean),
// compute t[b] = mean_row(b) @ Wv.T + bv.
// grid = (NB+1, DMODEL/64), block = 512 threads (8 waves).
// Each block recomputes the cheap 512-wide mean, then each wave computes 8
// output dims via coalesced float4 row reads + shfl reduction.
// ---------------------------------------------------------------------------
__global__ void k_mean_projv(const float* __restrict__ value,
                             const float* __restrict__ Wv,
                             const float* __restrict__ bv,
                             float* __restrict__ tout,
                             int NB) {
    __shared__ float m[DMODEL];
    const int b = blockIdx.x;
    const int c = blockIdx.y;
    const int tid = threadIdx.x;
    const int nrows = (b < NB) ? PER_BLK : NB * PER_BLK;

    float s = 0.f;
    for (int r = 0; r < nrows; ++r) {
        int row;
        if (b < NB) row = b * BLOCKLEN + r * STRIDE;
        else        row = (r / PER_BLK) * BLOCKLEN + (r % PER_BLK) * STRIDE;
        s += value[(size_t)row * DMODEL + tid];
    }
    m[tid] = s / (float)nrows;
    __syncthreads();

    const int wave = tid >> 6, lane = tid & 63;
    const float4* m4 = (const float4*)m;
    const float4 mA = m4[lane];
    const float4 mB = m4[lane + 64];

    for (int d0 = 0; d0 < 8; ++d0) {
        const int d = c * 64 + wave * 8 + d0;
        const float4* w4 = (const float4*)(Wv + (size_t)d * DMODEL);
        const float4 wA = w4[lane];
        const float4 wB = w4[lane + 64];
        float acc = wA.x*mA.x + wA.y*mA.y + wA.z*mA.z + wA.w*mA.w
                  + wB.x*mB.x + wB.y*mB.y + wB.z*mB.z + wB.w*mB.w;
        #pragma unroll
        for (int off = 32; off; off >>= 1) acc += __shfl_down(acc, off);
        if (lane == 0) tout[(size_t)b * DMODEL + d] = acc + bv[d];
    }
}

// ---------------------------------------------------------------------------
// Stage 2: y[b] = t[b] @ Wo.T + bo.  Same shape as stage 1.
// ---------------------------------------------------------------------------
__global__ void k_projo(const float* __restrict__ tin,
                        const float* __restrict__ Wo,
                        const float* __restrict__ bo,
                        float* __restrict__ y) {
    __shared__ float m[DMODEL];
    const int b = blockIdx.x;
    const int c = blockIdx.y;
    const int tid = threadIdx.x;

    m[tid] = tin[(size_t)b * DMODEL + tid];
    __syncthreads();

    const int wave = tid >> 6, lane = tid & 63;
    const float4* m4 = (const float4*)m;
    const float4 mA = m4[lane];
    const float4 mB = m4[lane + 64];

    for (int d0 = 0; d0 < 8; ++d0) {
        const int d = c * 64 + wave * 8 + d0;
        const float4* w4 = (const float4*)(Wo + (size_t)d * DMODEL);
        const float4 wA = w4[lane];
        const float4 wB = w4[lane + 64];
        float acc = wA.x*mA.x + wA.y*mA.y + wA.z*mA.z + wA.w*mA.w
                  + wB.x*mB.x + wB.y*mB.y + wB.z*mB.z + wB.w*mB.w;
        #pragma unroll
        for (int off = 32; off; off >>= 1) acc += __shfl_down(acc, off);
        if (lane == 0) y[(size_t)b * DMODEL + d] = acc + bo[d];
    }
}

// ---------------------------------------------------------------------------
// Stage 3: scatter the 11 rows to the full [S, D] output.
// grid = S blocks, 128 threads, one float4 per thread (coalesced 2KB/row).
// ---------------------------------------------------------------------------
__global__ void k_scatter(const float* __restrict__ y,
                          float* __restrict__ out,
                          int NB) {
    const int i = blockIdx.x;
    const int sel = ((i % BLOCKLEN) % STRIDE == 0) ? (i / BLOCKLEN) : NB;
    const float4* src = (const float4*)(y + (size_t)sel * DMODEL);
    float4* dst = (float4*)(out + (size_t)i * DMODEL);
    dst[threadIdx.x] = src[threadIdx.x];
}

extern "C" void kernel_launch(void* const* d_in, const int* in_sizes, int n_in,
                              void* d_out, int out_size, void* d_ws, size_t ws_size,
                              hipStream_t stream) {
    // setup_inputs order: query, key, value, Wq, bq, Wk, bk, Wv, bv, Wo, bo
    const float* value = (const float*)d_in[2];
    const float* Wv    = (const float*)d_in[7];
    const float* bv    = (const float*)d_in[8];
    const float* Wo    = (const float*)d_in[9];
    const float* bo    = (const float*)d_in[10];
    float* out = (float*)d_out;

    const int S  = in_sizes[0] / DMODEL;   // 4000
    const int NB = S / BLOCKLEN;           // 10

    float* t = (float*)d_ws;                         // (NB+1) x 512
    float* y = t + (size_t)(NB + 1) * DMODEL;        // (NB+1) x 512

    dim3 g1(NB + 1, DMODEL / 64);
    k_mean_projv<<<g1, 512, 0, stream>>>(value, Wv, bv, t, NB);
    k_projo<<<g1, 512, 0, stream>>>(t, Wo, bo, y);
    k_scatter<<<S, 128, 0, stream>>>(y, out, NB);
}

// Round 2
// 24.721 us; speedup vs baseline: 1.1205x; 1.1205x over previous
//
#include <hip/hip_runtime.h>

#define DMODEL 512
#define BLOCKLEN 400
#define STRIDE 50
#define PER_BLK 8   // BLOCKLEN / STRIDE
#define CHUNK 32    // output dims per K2 block

// ---------------------------------------------------------------------------
// K1: for each of the 11 "mean rows" (10 block-means + 1 global mean),
// compute t[b] = mean_row(b) @ Wv.T + bv.
// grid = (NB+1, DMODEL/64), block = 512 threads (8 waves).
// ---------------------------------------------------------------------------
__global__ void k_mean_projv(const float* __restrict__ value,
                             const float* __restrict__ Wv,
                             const float* __restrict__ bv,
                             float* __restrict__ tout,
                             int NB) {
    __shared__ float m[DMODEL];
    const int b = blockIdx.x;
    const int c = blockIdx.y;
    const int tid = threadIdx.x;
    const int nrows = (b < NB) ? PER_BLK : NB * PER_BLK;

    float s = 0.f;
    for (int r = 0; r < nrows; ++r) {
        int row;
        if (b < NB) row = b * BLOCKLEN + r * STRIDE;
        else        row = (r / PER_BLK) * BLOCKLEN + (r % PER_BLK) * STRIDE;
        s += value[(size_t)row * DMODEL + tid];
    }
    m[tid] = s / (float)nrows;
    __syncthreads();

    const int wave = tid >> 6, lane = tid & 63;
    const float4* m4 = (const float4*)m;
    const float4 mA = m4[lane];
    const float4 mB = m4[lane + 64];

    for (int d0 = 0; d0 < 8; ++d0) {
        const int d = c * 64 + wave * 8 + d0;
        const float4* w4 = (const float4*)(Wv + (size_t)d * DMODEL);
        const float4 wA = w4[lane];
        const float4 wB = w4[lane + 64];
        float acc = wA.x*mA.x + wA.y*mA.y + wA.z*mA.z + wA.w*mA.w
                  + wB.x*mB.x + wB.y*mB.y + wB.z*mB.z + wB.w*mB.w;
        #pragma unroll
        for (int off = 32; off; off >>= 1) acc += __shfl_down(acc, off);
        if (lane == 0) tout[(size_t)b * DMODEL + d] = acc + bv[d];
    }
}

// ---------------------------------------------------------------------------
// K2: fused y-projection + scatter.
// grid = (NB, DMODEL/CHUNK) = (10, 16), block = 512 threads.
// Block (b,c): y_b/y_g slice of CHUNK dims = t[b|global] @ Wo[cslice].T + bo,
// then writes those dims for all 400 rows of sequence-block b.
// ---------------------------------------------------------------------------
__global__ void k_y_scatter(const float* __restrict__ t,   // (NB+1) x 512
                            const float* __restrict__ Wo,
                            const float* __restrict__ bo,
                            float* __restrict__ out,
                            int NB) {
    __shared__ __align__(16) float ty[2][CHUNK];  // [0]=y_b slice, [1]=y_global slice
    const int b = blockIdx.x;        // 0..NB-1
    const int c = blockIdx.y;        // 0..15
    const int tid = threadIdx.x;
    const int wave = tid >> 6, lane = tid & 63;

    const float4* tb4 = (const float4*)(t + (size_t)b  * DMODEL);
    const float4* tg4 = (const float4*)(t + (size_t)NB * DMODEL);
    const float4 tbA = tb4[lane], tbB = tb4[lane + 64];
    const float4 tgA = tg4[lane], tgB = tg4[lane + 64];

    #pragma unroll
    for (int k = 0; k < 4; ++k) {
        const int dloc = wave * 4 + k;            // 0..31
        const int d = c * CHUNK + dloc;
        const float4* w4 = (const float4*)(Wo + (size_t)d * DMODEL);
        const float4 wA = w4[lane];
        const float4 wB = w4[lane + 64];
        float ab = wA.x*tbA.x + wA.y*tbA.y + wA.z*tbA.z + wA.w*tbA.w
                 + wB.x*tbB.x + wB.y*tbB.y + wB.z*tbB.z + wB.w*tbB.w;
        float ag = wA.x*tgA.x + wA.y*tgA.y + wA.z*tgA.z + wA.w*tgA.w
                 + wB.x*tgB.x + wB.y*tgB.y + wB.z*tgB.z + wB.w*tgB.w;
        #pragma unroll
        for (int off = 32; off; off >>= 1) {
            ab += __shfl_down(ab, off);
            ag += __shfl_down(ag, off);
        }
        if (lane == 0) {
            ty[0][dloc] = ab + bo[d];
            ty[1][dloc] = ag + bo[d];
        }
    }
    __syncthreads();

    // Scatter: rows [b*400, b*400+400), dims [c*32, c*32+32).
    const int rloc = tid >> 3;       // 0..63 (row within 64-row group)
    const int dq   = tid & 7;        // float4 index within the 32-dim slice
    const float4 vb = ((const float4*)&ty[0][0])[dq];
    const float4 vg = ((const float4*)&ty[1][0])[dq];

    #pragma unroll
    for (int r0 = 0; r0 < BLOCKLEN; r0 += 64) {
        const int rr = r0 + rloc;    // row within block b
        if (rr < BLOCKLEN) {
            const int i = b * BLOCKLEN + rr;
            const float4 v = ((rr % STRIDE) == 0) ? vb : vg;
            ((float4*)(out + (size_t)i * DMODEL + c * CHUNK))[dq] = v;
        }
    }
}

extern "C" void kernel_launch(void* const* d_in, const int* in_sizes, int n_in,
                              void* d_out, int out_size, void* d_ws, size_t ws_size,
                              hipStream_t stream) {
    // setup_inputs order: query, key, value, Wq, bq, Wk, bk, Wv, bv, Wo, bo
    const float* value = (const float*)d_in[2];
    const float* Wv    = (const float*)d_in[7];
    const float* bv    = (const float*)d_in[8];
    const float* Wo    = (const float*)d_in[9];
    const float* bo    = (const float*)d_in[10];
    float* out = (float*)d_out;

    const int S  = in_sizes[0] / DMODEL;   // 4000
    const int NB = S / BLOCKLEN;           // 10

    float* t = (float*)d_ws;               // (NB+1) x 512

    dim3 g1(NB + 1, DMODEL / 64);
    k_mean_projv<<<g1, 512, 0, stream>>>(value, Wv, bv, t, NB);

    dim3 g2(NB, DMODEL / CHUNK);
    k_y_scatter<<<g2, 512, 0, stream>>>(t, Wo, bo, out, NB);
}